// Round 3
// baseline (239.664 us; speedup 1.0000x reference)
//
#include <hip/hip_runtime.h>

// ---------------------------------------------------------------------------
// Conv2DQwenRMSNorm: y = x @ W^T, W = mean_l(conv_w); RMSNorm(y)*norm_w.
// B=4,S=4096 -> M=16384; H=1024 (N=K).
//
// R3: grid 256 x 1024 threads (16 waves, 4/SIMD, VGPR<=128).
//  - A panel (64 rows x 1024 k, bf16, frag-major, xor-swizzled) in LDS once.
//  - B frags global->VGPR from L2-resident frag-major W (wprep output).
//  - Wave w: row-tile (w&1), col-tiles 4*(w>>1)..+3. Wave PAIRS share the
//    same B frags -> second read hits L1, halving L2 traffic.
//  - Depth-2 register pipeline, no barriers in K loop. Fused RMSNorm epilogue.
// ---------------------------------------------------------------------------

using bf16x8 = __attribute__((ext_vector_type(8))) short;
using f32x16 = __attribute__((ext_vector_type(16))) float;

#define NDIM 1024
#define MTILE 64

__device__ __forceinline__ unsigned short f2bf(float f) {
    unsigned u = __float_as_uint(f);
    u += 0x7fffu + ((u >> 16) & 1u);          // RNE
    return (unsigned short)(u >> 16);
}

// ---- Kernel 1: W = mean_l conv_w, bf16, fragment-major ---------------------
// thread -> one float4 (4 k-elems) of one output row o; 20 strided loads.
__global__ __launch_bounds__(256) void wprep_kernel(const float* __restrict__ cw,
                                                    unsigned short* __restrict__ Wf) {
    const int idx = blockIdx.x * 256 + threadIdx.x;  // 0..262143
    const int o   = idx >> 8;                        // row 0..1023
    const int q   = idx & 255;                       // float4 index in row
    const float* p = cw + (size_t)o * NDIM + (q << 2);
    float4 s = make_float4(0.f, 0.f, 0.f, 0.f);
#pragma unroll
    for (int l = 0; l < 20; ++l) {
        float4 v = *(const float4*)(p + (size_t)l * (NDIM * NDIM));
        s.x += v.x; s.y += v.y; s.z += v.z; s.w += v.w;
    }
    const float sc = 0.05f;                          // 1/L
    ushort4 o4;
    o4.x = f2bf(s.x * sc); o4.y = f2bf(s.y * sc);
    o4.z = f2bf(s.z * sc); o4.w = f2bf(s.w * sc);
    const int ct  = o >> 5, ml = o & 31;
    const int k16 = q >> 2, h = (q >> 1) & 1, half = q & 1;
    // frag-major: frag(ct,k16)=1KB; slot lane=(h*32+ml) holds W[ct*32+ml][k16*16+h*8..+7]
    *(ushort4*)((char*)Wf + ((((ct << 6) + k16) << 10)) + (((h << 5) + ml) << 4) + (half << 3)) = o4;
}

// ---- Kernel 2: fused GEMM + RMSNorm ---------------------------------------
__global__ __launch_bounds__(1024, 4) void gemm_rms_kernel(
        const float* __restrict__ x, const unsigned short* __restrict__ Wf,
        const float* __restrict__ nw, float* __restrict__ out) {
    __shared__ short lAf[MTILE * NDIM];              // 128 KB, frag-major
    __shared__ float rowss[MTILE];

    const int tid  = threadIdx.x;
    const int wv   = tid >> 6;                       // 0..15
    const int lane = tid & 63;
    const int ml   = lane & 31;
    const int h    = lane >> 5;
    const int g    = wv >> 1;                        // col group 0..7
    const int tr   = wv & 1;                         // row tile
    const int row0 = blockIdx.x * MTILE;

    if (tid < MTILE) rowss[tid] = 0.f;

    // ---- stage A panel: 64 rows x 1024 k, fp32->bf16, frag-major + swizzle --
    {
        const int row = tid >> 4;                    // 0..63
        const int rt  = row >> 5, rml = row & 31;
        const int j   = tid & 15;
        const float* xr = x + (size_t)(row0 + row) * NDIM;
#pragma unroll
        for (int it = 0; it < 8; ++it) {
            const int k0 = (j << 3) + (it << 7);     // 8-elem chunk base
            float4 v0 = *(const float4*)(xr + k0);
            float4 v1 = *(const float4*)(xr + k0 + 4);
            bf16x8 c;
            c[0] = (short)f2bf(v0.x); c[1] = (short)f2bf(v0.y);
            c[2] = (short)f2bf(v0.z); c[3] = (short)f2bf(v0.w);
            c[4] = (short)f2bf(v1.x); c[5] = (short)f2bf(v1.y);
            c[6] = (short)f2bf(v1.z); c[7] = (short)f2bf(v1.w);
            const int k16 = k0 >> 4, hh = (k0 >> 3) & 1;
            const int slot = ((hh << 5) + rml) ^ (k16 & 7);
            *(bf16x8*)((char*)lAf + (((rt << 6) + k16) << 10) + (slot << 4)) = c;
        }
    }
    __syncthreads();

    // ---- K loop: depth-2 register pipeline, no barriers ----
    const char* bBase = (const char*)Wf + (((size_t)(g << 2) << 6) << 10) + (lane << 4);
    const char* aBase = (const char*)lAf + ((size_t)(tr << 6) << 10);

    f32x16 acc[4];
#pragma unroll
    for (int tc = 0; tc < 4; ++tc)
#pragma unroll
        for (int r = 0; r < 16; ++r) acc[tc][r] = 0.f;

    bf16x8 af[2], bfr[2][4];
#pragma unroll
    for (int k = 0; k < 2; ++k) {
        af[k] = *(const bf16x8*)(aBase + (k << 10) + ((lane ^ (k & 7)) << 4));
#pragma unroll
        for (int c = 0; c < 4; ++c)
            bfr[k][c] = *(const bf16x8*)(bBase + (((c << 6) + k) << 10));
    }

#pragma unroll
    for (int k16 = 0; k16 < 64; ++k16) {
        const int cur = k16 & 1;
        bf16x8 a  = af[cur];
        bf16x8 b0 = bfr[cur][0], b1 = bfr[cur][1], b2 = bfr[cur][2], b3 = bfr[cur][3];
        if (k16 + 2 < 64) {
            const int kn = k16 + 2;
            af[cur] = *(const bf16x8*)(aBase + (kn << 10) + ((lane ^ (kn & 7)) << 4));
#pragma unroll
            for (int c = 0; c < 4; ++c)
                bfr[cur][c] = *(const bf16x8*)(bBase + (((c << 6) + kn) << 10));
        }
        acc[0] = __builtin_amdgcn_mfma_f32_32x32x16_bf16(a, b0, acc[0], 0, 0, 0);
        acc[1] = __builtin_amdgcn_mfma_f32_32x32x16_bf16(a, b1, acc[1], 0, 0, 0);
        acc[2] = __builtin_amdgcn_mfma_f32_32x32x16_bf16(a, b2, acc[2], 0, 0, 0);
        acc[3] = __builtin_amdgcn_mfma_f32_32x32x16_bf16(a, b3, acc[3], 0, 0, 0);
    }

    // ---- epilogue: fused RMSNorm ----
    __syncthreads();                                 // rowss init visible
    // C/D layout (32x32): col = lane&31, row = (r&3) + 8*(r>>2) + 4*(lane>>5)
#pragma unroll
    for (int r = 0; r < 16; ++r) {
        float v = 0.f;
#pragma unroll
        for (int tc = 0; tc < 4; ++tc) { float a = acc[tc][r]; v += a * a; }
#pragma unroll
        for (int m = 1; m <= 16; m <<= 1) v += __shfl_xor(v, m, 64);
        if (ml == 0)
            atomicAdd(&rowss[tr * 32 + (r & 3) + 8 * (r >> 2) + 4 * h], v);
    }
    __syncthreads();
    if (tid < MTILE) rowss[tid] = rsqrtf(rowss[tid] * (1.0f / 1024.0f) + 1e-6f);
    __syncthreads();

    float nwv[4];
#pragma unroll
    for (int tc = 0; tc < 4; ++tc) nwv[tc] = nw[(g << 7) + tc * 32 + ml];

#pragma unroll
    for (int r = 0; r < 16; ++r) {
        const int m = tr * 32 + (r & 3) + 8 * (r >> 2) + 4 * h;
        const float rs = rowss[m];
        float* orow = out + (size_t)(row0 + m) * NDIM + (g << 7) + ml;
#pragma unroll
        for (int tc = 0; tc < 4; ++tc)
            orow[tc * 32] = acc[tc][r] * rs * nwv[tc];
    }
}

extern "C" void kernel_launch(void* const* d_in, const int* in_sizes, int n_in,
                              void* d_out, int out_size, void* d_ws, size_t ws_size,
                              hipStream_t stream) {
    const float* x  = (const float*)d_in[0];
    const float* cw = (const float*)d_in[1];
    const float* nw = (const float*)d_in[2];
    float* out = (float*)d_out;
    unsigned short* Wf = (unsigned short*)d_ws;   // 2 MB fragment-major W

    hipLaunchKernelGGL(wprep_kernel, dim3(1024), dim3(256), 0, stream, cw, Wf);
    hipLaunchKernelGGL(gemm_rms_kernel, dim3(256), dim3(1024), 0, stream, x, Wf, nw, out);
}

// Round 4
// 221.747 us; speedup vs baseline: 1.0808x; 1.0808x over previous
//
#include <hip/hip_runtime.h>

// ---------------------------------------------------------------------------
// Conv2DQwenRMSNorm: y = x @ W^T, W = mean_l(conv_w); RMSNorm(y)*norm_w.
// B=4,S=4096 -> M=16384; H=1024 (N=K).
//
// R4: R2 skeleton (256 blocks x 512 thr, 8 waves, wave = 2x4 tiles 32x32,
// full-N rows for fused RMSNorm) plus:
//  - NONTEMPORAL x loads / out stores -> streaming data can't evict W from L2
//  - per-block K-phase stagger -> decorrelate 256 CUs' L2 address streams
//  - depth-4 B register pipeline (16 loads in flight, FIFO), depth-2 A
// ---------------------------------------------------------------------------

using bf16x8 = __attribute__((ext_vector_type(8))) short;
using f32x16 = __attribute__((ext_vector_type(16))) float;
using f32x4  = __attribute__((ext_vector_type(4))) float;

#define NDIM 1024
#define MTILE 64

__device__ __forceinline__ unsigned short f2bf(float f) {
    unsigned u = __float_as_uint(f);
    u += 0x7fffu + ((u >> 16) & 1u);          // RNE
    return (unsigned short)(u >> 16);
}

// ---- Kernel 1: W = mean_l conv_w, bf16, fragment-major ---------------------
__global__ __launch_bounds__(256) void wprep_kernel(const float* __restrict__ cw,
                                                    unsigned short* __restrict__ Wf) {
    const int idx = blockIdx.x * 256 + threadIdx.x;  // 0..262143
    const int o   = idx >> 8;                        // row 0..1023
    const int q   = idx & 255;                       // float4 index in row
    const float* p = cw + (size_t)o * NDIM + (q << 2);
    f32x4 s = {0.f, 0.f, 0.f, 0.f};
#pragma unroll
    for (int l = 0; l < 20; ++l) {
        f32x4 v = __builtin_nontemporal_load((const f32x4*)(p + (size_t)l * (NDIM * NDIM)));
        s += v;
    }
    const float sc = 0.05f;                          // 1/L
    ushort4 o4;
    o4.x = f2bf(s[0] * sc); o4.y = f2bf(s[1] * sc);
    o4.z = f2bf(s[2] * sc); o4.w = f2bf(s[3] * sc);
    const int ct  = o >> 5, ml = o & 31;
    const int k16 = q >> 2, h = (q >> 1) & 1, half = q & 1;
    // frag-major: frag(ct,k16)=1KB; slot lane=(h*32+ml) holds W[ct*32+ml][k16*16+h*8..+7]
    *(ushort4*)((char*)Wf + (((ct << 6) + k16) << 10) + (((h << 5) + ml) << 4) + (half << 3)) = o4;
}

// ---- Kernel 2: fused GEMM + RMSNorm ---------------------------------------
__global__ __launch_bounds__(512, 2) void gemm_rms_kernel(
        const float* __restrict__ x, const unsigned short* __restrict__ Wf,
        const float* __restrict__ nw, float* __restrict__ out) {
    __shared__ short lAf[MTILE * NDIM];              // 128 KB, frag-major
    __shared__ float rowss[MTILE];

    const int tid  = threadIdx.x;
    const int wv   = tid >> 6;                       // 0..7
    const int lane = tid & 63;
    const int ml   = lane & 31;
    const int h    = lane >> 5;
    const int row0 = blockIdx.x * MTILE;
    const int phase = (blockIdx.x * 37) & 63;        // L2 decorrelation

    if (tid < MTILE) rowss[tid] = 0.f;

    // ---- stage A panel: 64 rows x 1024 k, fp32->bf16, frag-major + swizzle --
    {
        const int row = tid >> 3;                    // 0..63
        const int rt  = row >> 5, rml = row & 31;
        const float* xr = x + (size_t)(row0 + row) * NDIM;
#pragma unroll
        for (int it = 0; it < 16; ++it) {
            const int k0 = ((tid & 7) << 3) + (it << 6);   // 8-elem chunk base
            f32x4 v0 = __builtin_nontemporal_load((const f32x4*)(xr + k0));
            f32x4 v1 = __builtin_nontemporal_load((const f32x4*)(xr + k0 + 4));
            bf16x8 c;
            c[0] = (short)f2bf(v0[0]); c[1] = (short)f2bf(v0[1]);
            c[2] = (short)f2bf(v0[2]); c[3] = (short)f2bf(v0[3]);
            c[4] = (short)f2bf(v1[0]); c[5] = (short)f2bf(v1[1]);
            c[6] = (short)f2bf(v1[2]); c[7] = (short)f2bf(v1[3]);
            const int k16 = k0 >> 4, hh = (k0 >> 3) & 1;
            const int slot = ((hh << 5) + rml) ^ (k16 & 7);
            *(bf16x8*)((char*)lAf + (((rt << 6) + k16) << 10) + (slot << 4)) = c;
        }
    }
    __syncthreads();

    // ---- K loop: depth-4 B / depth-2 A register pipeline, no barriers ----
    const char* bB[4];
#pragma unroll
    for (int c = 0; c < 4; ++c)
        bB[c] = (const char*)Wf + ((((wv << 2) + c) << 6) << 10) + (lane << 4);

    f32x16 acc[2][4];
#pragma unroll
    for (int tr = 0; tr < 2; ++tr)
#pragma unroll
        for (int tc = 0; tc < 4; ++tc)
#pragma unroll
            for (int r = 0; r < 16; ++r) acc[tr][tc][r] = 0.f;

    bf16x8 af[2][2], bfr[4][4];
#pragma unroll
    for (int d = 0; d < 4; ++d) {
        const int k = (d + phase) & 63;
#pragma unroll
        for (int c = 0; c < 4; ++c)
            bfr[d][c] = *(const bf16x8*)(bB[c] + (k << 10));
    }
#pragma unroll
    for (int d = 0; d < 2; ++d) {
        const int k = (d + phase) & 63;
#pragma unroll
        for (int tr = 0; tr < 2; ++tr)
            af[d][tr] = *(const bf16x8*)((const char*)lAf +
                        (((tr << 6) + k) << 10) + ((lane ^ (k & 7)) << 4));
    }

#pragma unroll 4
    for (int i = 0; i < 64; ++i) {
        const int bb = i & 3, ab = i & 1;
        bf16x8 a0 = af[ab][0], a1 = af[ab][1];
        bf16x8 b0 = bfr[bb][0], b1 = bfr[bb][1], b2 = bfr[bb][2], b3 = bfr[bb][3];
        if (i + 4 < 64) {
            const int kn = (i + 4 + phase) & 63;
#pragma unroll
            for (int c = 0; c < 4; ++c)
                bfr[bb][c] = *(const bf16x8*)(bB[c] + (kn << 10));
        }
        if (i + 2 < 64) {
            const int kn = (i + 2 + phase) & 63;
#pragma unroll
            for (int tr = 0; tr < 2; ++tr)
                af[ab][tr] = *(const bf16x8*)((const char*)lAf +
                             (((tr << 6) + kn) << 10) + ((lane ^ (kn & 7)) << 4));
        }
        acc[0][0] = __builtin_amdgcn_mfma_f32_32x32x16_bf16(a0, b0, acc[0][0], 0, 0, 0);
        acc[0][1] = __builtin_amdgcn_mfma_f32_32x32x16_bf16(a0, b1, acc[0][1], 0, 0, 0);
        acc[0][2] = __builtin_amdgcn_mfma_f32_32x32x16_bf16(a0, b2, acc[0][2], 0, 0, 0);
        acc[0][3] = __builtin_amdgcn_mfma_f32_32x32x16_bf16(a0, b3, acc[0][3], 0, 0, 0);
        acc[1][0] = __builtin_amdgcn_mfma_f32_32x32x16_bf16(a1, b0, acc[1][0], 0, 0, 0);
        acc[1][1] = __builtin_amdgcn_mfma_f32_32x32x16_bf16(a1, b1, acc[1][1], 0, 0, 0);
        acc[1][2] = __builtin_amdgcn_mfma_f32_32x32x16_bf16(a1, b2, acc[1][2], 0, 0, 0);
        acc[1][3] = __builtin_amdgcn_mfma_f32_32x32x16_bf16(a1, b3, acc[1][3], 0, 0, 0);
    }

    // ---- epilogue: fused RMSNorm ----
    __syncthreads();                                 // rowss init visible
    // C/D layout (32x32): col = lane&31, row = (r&3) + 8*(r>>2) + 4*(lane>>5)
#pragma unroll
    for (int tr = 0; tr < 2; ++tr) {
#pragma unroll
        for (int r = 0; r < 16; ++r) {
            float v = 0.f;
#pragma unroll
            for (int tc = 0; tc < 4; ++tc) { float a = acc[tr][tc][r]; v += a * a; }
#pragma unroll
            for (int m = 1; m <= 16; m <<= 1) v += __shfl_xor(v, m, 64);
            if (ml == 0)
                atomicAdd(&rowss[tr * 32 + (r & 3) + 8 * (r >> 2) + 4 * h], v);
        }
    }
    __syncthreads();
    if (tid < MTILE) rowss[tid] = rsqrtf(rowss[tid] * (1.0f / 1024.0f) + 1e-6f);
    __syncthreads();

    float nwv[4];
#pragma unroll
    for (int tc = 0; tc < 4; ++tc) nwv[tc] = nw[(wv << 7) + tc * 32 + ml];

#pragma unroll
    for (int tr = 0; tr < 2; ++tr) {
#pragma unroll
        for (int r = 0; r < 16; ++r) {
            const int m = tr * 32 + (r & 3) + 8 * (r >> 2) + 4 * h;
            const float rs = rowss[m];
            float* orow = out + (size_t)(row0 + m) * NDIM + (wv << 7) + ml;
#pragma unroll
            for (int tc = 0; tc < 4; ++tc)
                __builtin_nontemporal_store(acc[tr][tc][r] * rs * nwv[tc], orow + tc * 32);
        }
    }
}

extern "C" void kernel_launch(void* const* d_in, const int* in_sizes, int n_in,
                              void* d_out, int out_size, void* d_ws, size_t ws_size,
                              hipStream_t stream) {
    const float* x  = (const float*)d_in[0];
    const float* cw = (const float*)d_in[1];
    const float* nw = (const float*)d_in[2];
    float* out = (float*)d_out;
    unsigned short* Wf = (unsigned short*)d_ws;   // 2 MB fragment-major W

    hipLaunchKernelGGL(wprep_kernel, dim3(1024), dim3(256), 0, stream, cw, Wf);
    hipLaunchKernelGGL(gemm_rms_kernel, dim3(256), dim3(512), 0, stream, x, Wf, nw, out);
}